// Round 9
// baseline (678.236 us; speedup 1.0000x reference)
//
#include <hip/hip_runtime.h>

typedef unsigned short u16;
typedef __attribute__((ext_vector_type(8))) short short8;
typedef __attribute__((ext_vector_type(4))) float floatx4;
typedef __attribute__((ext_vector_type(4), aligned(4))) float floatx4u;   // unaligned-safe vector load

// ---------- bf16 helpers (RNE) ----------
__device__ __forceinline__ float bf2f(u16 u) {
    return __uint_as_float(((unsigned int)u) << 16);
}
__device__ __forceinline__ u16 f2bf(float f) {
    unsigned int i = __float_as_uint(f);
    unsigned int r = i + 0x7FFFu + ((i >> 16) & 1u);
    return (u16)(r >> 16);
}
// relu on two packed bf16 (zero halves with sign bit set)
__device__ __forceinline__ unsigned int relu2(unsigned int x) {
    unsigned int m = (((x >> 15) & 1u) * 0x0000FFFFu) | ((x >> 31) * 0xFFFF0000u);
    return x & ~m;
}

// ---------- async global->LDS (16B per lane, wave-uniform LDS base) ----------
typedef __attribute__((address_space(3))) void lds_void;
typedef const __attribute__((address_space(1))) void g_void;
__device__ __forceinline__ void async_copy16(const void* g, void* l) {
    __builtin_amdgcn_global_load_lds((g_void*)g, (lds_void*)l, 16, 0, 0);
}

__device__ __forceinline__ void acc_bf8(float* a8, uint4 u, float wj) {
    a8[0] += wj * __uint_as_float(u.x << 16);
    a8[1] += wj * __uint_as_float(u.x & 0xffff0000u);
    a8[2] += wj * __uint_as_float(u.y << 16);
    a8[3] += wj * __uint_as_float(u.y & 0xffff0000u);
    a8[4] += wj * __uint_as_float(u.z << 16);
    a8[5] += wj * __uint_as_float(u.z & 0xffff0000u);
    a8[6] += wj * __uint_as_float(u.w << 16);
    a8[7] += wj * __uint_as_float(u.w & 0xffff0000u);
}

#define MFMA16(a, b, c) __builtin_amdgcn_mfma_f32_16x16x32_bf16(a, b, c, 0, 0, 0)

// ================= problem constants =================
#define E_BONDS 131072
#define N_ATOMS_C 65536
#define KPAD_I 160     // 157 padded
#define KPAD_O 416     // 399 padded
#define N_MOLS 2048

// ================= prep kernels =================
// W [K,256] f32 -> Wt [256, Kpad] bf16 (transposed, zero-padded)
__global__ __launch_bounds__(256) void prep_wt(const float* __restrict__ W, u16* __restrict__ Wt, int K, int Kpad) {
    int idx = blockIdx.x * 256 + threadIdx.x;           // 256*Kpad total
    int n = idx / Kpad;
    int k = idx - n * Kpad;
    float v = (k < K) ? W[(size_t)k * 256 + n] : 0.f;
    Wt[idx] = f2bf(v);
}

// W_o_w [399,256] -> reordered transposed [256,416]
__global__ __launch_bounds__(256) void prep_wo(const float* __restrict__ W, u16* __restrict__ Wt) {
    int idx = blockIdx.x * 256 + threadIdx.x;           // 256*416 total
    int n = idx / KPAD_O;
    int k = idx - n * KPAD_O;
    float v = 0.f;
    if (k < 256)      v = W[(size_t)(143 + k) * 256 + n];
    else if (k < 399) v = W[(size_t)(k - 256) * 256 + n];
    Wt[idx] = f2bf(v);
}

// ================= MFMA GEMM, N=256 full width: C[M,256] = epi(A[M,K] @ Bt[256,K]^T) =================
// EPI: 0 plain->out ; 1 out=pre, tout=relu(pre).wma score ; 3 out=relu(acc+bias)
// RELUA: apply bf16-relu to A during staging. F32A: A staged from raw f32 rows (width 157, fbonds),
//   coalesced mapping row=tid>>2, kb=tid&3 (R7 lesson: row=tid&127 was latency-bound, 104us).
// 512 thr = 8 waves x 16 rows; M-tile 128; acc[16] = 64 AGPR/wave.
template <int EPI, bool RELUA, bool F32A>
__global__ __launch_bounds__(512, 3) void gemm256(
    const u16* __restrict__ A, const u16* __restrict__ Bt,
    u16* __restrict__ out,
    const float* __restrict__ bias, const float* __restrict__ wma,
    float* __restrict__ tout, int K, const float* __restrict__ Af32)
{
    __shared__ char ldsbuf[33792];     // stage: Al 8192 + Bl 16384 = 24576 ; epi: 8 waves x 4224
    u16* Al = (u16*)ldsbuf;            // [kb=4][row=128][8]
    u16* Bl = (u16*)(ldsbuf + 8192);   // [kb=4][n=256][8]

    const int tid = threadIdx.x;
    const int w = tid >> 6, lane = tid & 63;
    const int quad = lane >> 4, mr = lane & 15;
    const int m0 = blockIdx.x * 128;

    floatx4 acc[16] = {};

    const u16* Ag = F32A ? nullptr : (A + (size_t)(m0 + (tid & 127)) * K + ((tid >> 7) << 3));
    const float* Af = F32A ? (Af32 + (size_t)(m0 + (tid >> 2)) * 157) : nullptr;

    for (int k0 = 0; k0 < K; k0 += 32) {
        if (F32A) {
            const int kb = tid & 3;
            const int cb = k0 + kb * 8;
            short8 xv;
            if (cb + 8 <= 157) {
                floatx4u v0 = *(const floatx4u*)(Af + cb);
                floatx4u v1 = *(const floatx4u*)(Af + cb + 4);
                xv[0] = (short)f2bf(v0.x); xv[1] = (short)f2bf(v0.y);
                xv[2] = (short)f2bf(v0.z); xv[3] = (short)f2bf(v0.w);
                xv[4] = (short)f2bf(v1.x); xv[5] = (short)f2bf(v1.y);
                xv[6] = (short)f2bf(v1.z); xv[7] = (short)f2bf(v1.w);
            } else {
#pragma unroll
                for (int e = 0; e < 8; ++e) {
                    int c = cb + e;
                    float v = (c < 157) ? Af[c] : 0.f;
                    xv[e] = (short)f2bf(v);
                }
            }
            *(short8*)(Al + ((kb << 7) + (tid >> 2)) * 8) = xv;
        } else if (RELUA) {
            uint4 x = *(const uint4*)(Ag + k0);
            x.x = relu2(x.x); x.y = relu2(x.y); x.z = relu2(x.z); x.w = relu2(x.w);
            *(uint4*)(Al + tid * 8) = x;
        } else {
            async_copy16(Ag + k0, Al + tid * 8);
        }
#pragma unroll
        for (int i = 0; i < 2; ++i) {
            int c = tid + i * 512;
            async_copy16(Bt + (size_t)(c & 255) * K + k0 + ((c >> 8) << 3), Bl + c * 8);
        }
        __syncthreads();

        short8 af = *(const short8*)(Al + quad * 1024 + (w * 16 + mr) * 8);
#pragma unroll
        for (int j = 0; j < 16; ++j) {
            short8 bf = *(const short8*)(Bl + quad * 2048 + (j * 16 + mr) * 8);
            acc[j] = MFMA16(af, bf, acc[j]);
        }
        __syncthreads();
    }

    // ---- coalesced epilogue: two 8-row passes through a wave-private LDS slice ----
    u16* slice = (u16*)ldsbuf + w * 2112;       // 8 rows x 264 u16 = 4224 B
    const int lhalf = lane >> 5;
    const int lcol = (lane & 31) * 8;
    float wmal8[8];
    if (EPI == 1) {
#pragma unroll
        for (int e = 0; e < 8; ++e) wmal8[e] = wma[lcol + e];
    }
    float bl16[16];
    if (EPI == 3) {
#pragma unroll
        for (int j = 0; j < 16; ++j) bl16[j] = bias[j * 16 + mr];
    }

#pragma unroll
    for (int p = 0; p < 2; ++p) {
        if ((quad >> 1) == p) {
            int lr = (quad & 1) * 4;
#pragma unroll
            for (int j = 0; j < 16; ++j)
#pragma unroll
                for (int r = 0; r < 4; ++r) {
                    float v = acc[j][r];
                    if (EPI == 3) { v += bl16[j]; v = v > 0.f ? v : 0.f; }
                    slice[(lr + r) * 264 + j * 16 + mr] = f2bf(v);
                }
        }
        __syncthreads();
#pragma unroll
        for (int round = 0; round < 4; ++round) {
            int rowl = round * 2 + lhalf;
            int row = m0 + w * 16 + p * 8 + rowl;
            size_t off = (size_t)row * 256 + lcol;
            short8 pv = *(const short8*)(slice + rowl * 264 + lcol);
            if (EPI == 0 || EPI == 3) {
                *(short8*)(out + off) = pv;
            } else {   // EPI 1: store pre; score from relu(pre)
                *(short8*)(out + off) = pv;
                float pdot = 0.f;
#pragma unroll
                for (int e = 0; e < 8; ++e) {
                    u16 u = (u16)pv[e];
                    u = (u & 0x8000u) ? (u16)0 : u;
                    pdot += bf2f(u) * wmal8[e];
                }
                pdot += __shfl_xor(pdot, 1); pdot += __shfl_xor(pdot, 2);
                pdot += __shfl_xor(pdot, 4); pdot += __shfl_xor(pdot, 8);
                pdot += __shfl_xor(pdot, 16);
                if ((lane & 31) == 0) tout[row] = pdot;
            }
        }
        __syncthreads();
    }
}

// ================= fused gather + GEMM, barrier-free K-loop (R2 geometry) =================
// Linearity: (sum_j w_j * msg[b_j]) @ W == sum_j w_j * (msg[b_j] @ W).
// 512 thr = 8 waves, MT=64. B (L2-resident weight panel) read per-wave directly from global
// as MFMA fragments -> no LDS B staging, no K-loop barriers. acc[MF][2] = 32 VGPR.
// NOTE (R6): nontemporal hints HURT (NT stores lose L2 write-combining: WRITE 66->108MB). Plain ops.
// MODE 0: iter — A[r] = sum_j softmax(t[b_j]) * msg_prev[b_j]; epi: msg = relu(binput + acc), t_out = msg.wma
// MODE 1: iter1 — like MODE 0 but gathers binput rows with relu-on-load (msg0 = relu(binput))
// MODE 2: atom — A[r] = [sum_j msg[a_j] | fatoms_row | 0-pad], K=416; epi: atomh = relu(acc + bias);
//         then SECOND GEMM from the atomh LDS bounce: hW = atomh @ Bt2 (wta panel) -> out2.
template <int MODE>
__global__ __launch_bounds__(512, 6) void fused_gg(
    const u16* src, const u16* __restrict__ Bt, const int* __restrict__ graph,
    const float* __restrict__ t_in, const u16* __restrict__ binput,
    const float* __restrict__ fatoms, const float* __restrict__ bias,
    const float* __restrict__ wma, u16* __restrict__ outp, float* __restrict__ t_out,
    const u16* __restrict__ Bt2, u16* __restrict__ out2)
{
    constexpr int MT = (MODE == 2) ? 32 : 64;       // M tile (rows)
    constexpr int KK = (MODE == 2) ? 416 : 256;     // K
    constexpr int KP = KK + 8;                      // padded A stride (u16)
    constexpr int MF = MT / 16;                     // m-fragments per wave (4 or 2)
    constexpr int LDSB = (MODE == 2) ? (32 * 424 * 2) : (32 * 268 * 4);   // 27136 / 34304

    __shared__ __align__(16) char ldsbuf[LDSB];
    u16* As = (u16*)ldsbuf;             // [MT][KP]

    const int tid = threadIdx.x;
    const int w = tid >> 6, lane = tid & 63;
    const int quad = lane >> 4, mr = lane & 15;
    const int hw = tid >> 5, l32 = tid & 31;
    const int m0 = blockIdx.x * MT;

    // ---------- gather phase: build A tile in LDS (half-wave per row, 16 half-waves) ----------
    for (int it = 0; it < MT / 16; ++it) {
        const int r = it * 16 + hw;
        const int e = m0 + r;
        const int* bg = graph + (size_t)e * 6;
        int2 b01 = *(const int2*)bg;
        int2 b23 = *(const int2*)(bg + 2);
        int2 b45 = *(const int2*)(bg + 4);
        int b[6] = {b01.x, b01.y, b23.x, b23.y, b45.x, b45.y};

        float wg[6];
        if (MODE != 2) {
            float s[6];
#pragma unroll
            for (int j = 0; j < 6; ++j) s[j] = t_in[b[j]];
            float mx = fmaxf(fmaxf(fmaxf(s[0], s[1]), fmaxf(s[2], s[3])), fmaxf(s[4], s[5]));
            float den = 0.f;
#pragma unroll
            for (int j = 0; j < 6; ++j) { wg[j] = __expf(s[j] - mx); den += wg[j]; }
            float inv = 1.f / den;
#pragma unroll
            for (int j = 0; j < 6; ++j) wg[j] *= inv;
        }

        float a8[8] = {};
#pragma unroll
        for (int j = 0; j < 6; ++j) {
            uint4 u = *(const uint4*)(src + (size_t)b[j] * 256 + l32 * 8);
            if (MODE == 1) { u.x = relu2(u.x); u.y = relu2(u.y); u.z = relu2(u.z); u.w = relu2(u.w); }
            acc_bf8(a8, u, (MODE == 2) ? 1.f : wg[j]);
        }
        short8 mv;
#pragma unroll
        for (int k = 0; k < 8; ++k) mv[k] = (short)f2bf(a8[k]);
        *(short8*)(As + r * KP + l32 * 8) = mv;

        if (MODE == 2) {
            const float* frow = fatoms + (size_t)e * 143;
#pragma unroll
            for (int i = 0; i < 5; ++i) {
                int c = l32 + i * 32;
                As[r * KP + 256 + c] = (c < 143) ? f2bf(frow[c]) : (u16)0;
            }
        }
    }
    __syncthreads();

    // ---------- barrier-free K-loop: B frags straight from global (L2-hit), A from LDS ----------
    floatx4 acc[MF][2] = {};
    const u16* bp0 = Bt + (size_t)(w * 32 + mr) * KK + quad * 8;
    const u16* bp1 = bp0 + (size_t)16 * KK;
#pragma unroll 2
    for (int ks = 0; ks < KK / 32; ++ks) {
        const int k0 = ks * 32;
        short8 bf0 = *(const short8*)(bp0 + k0);
        short8 bf1 = *(const short8*)(bp1 + k0);
#pragma unroll
        for (int mf = 0; mf < MF; ++mf) {
            short8 af = *(const short8*)(As + (mf * 16 + mr) * KP + k0 + quad * 8);
            acc[mf][0] = MFMA16(af, bf0, acc[mf][0]);
            acc[mf][1] = MFMA16(af, bf1, acc[mf][1]);
        }
    }
    __syncthreads();                    // all As reads done before bounce overwrite

    // ---------- epilogue ----------
    if (MODE != 2) {
        // f32 bounce (keeps acc full precision through binput add) in two 32-row passes
        float* Pf = (float*)ldsbuf;     // [32][268] f32
        const int rrow = tid >> 4;      // 0..31
        const int rcol = (tid & 15) * 16;
        float wv[16];
#pragma unroll
        for (int e2 = 0; e2 < 16; ++e2) wv[e2] = wma[rcol + e2];

#pragma unroll
        for (int p = 0; p < 2; ++p) {
#pragma unroll
            for (int mi = 0; mi < 2; ++mi) {
#pragma unroll
                for (int jj = 0; jj < 2; ++jj)
#pragma unroll
                    for (int r = 0; r < 4; ++r)
                        Pf[(mi * 16 + quad * 4 + r) * 268 + (w * 2 + jj) * 16 + mr] = acc[p * 2 + mi][jj][r];
            }
            __syncthreads();
            const int grow = m0 + p * 32 + rrow;
            const u16* brow = binput + (size_t)grow * 256 + rcol;
            uint4 bu0 = *(const uint4*)brow;
            uint4 bu1 = *(const uint4*)(brow + 8);
            float bv[16] = {
                __uint_as_float(bu0.x << 16), __uint_as_float(bu0.x & 0xffff0000u),
                __uint_as_float(bu0.y << 16), __uint_as_float(bu0.y & 0xffff0000u),
                __uint_as_float(bu0.z << 16), __uint_as_float(bu0.z & 0xffff0000u),
                __uint_as_float(bu0.w << 16), __uint_as_float(bu0.w & 0xffff0000u),
                __uint_as_float(bu1.x << 16), __uint_as_float(bu1.x & 0xffff0000u),
                __uint_as_float(bu1.y << 16), __uint_as_float(bu1.y & 0xffff0000u),
                __uint_as_float(bu1.z << 16), __uint_as_float(bu1.z & 0xffff0000u),
                __uint_as_float(bu1.w << 16), __uint_as_float(bu1.w & 0xffff0000u)};
            const float* prow = Pf + rrow * 268 + rcol;
            float pdot = 0.f;
            short8 o0, o1;
#pragma unroll
            for (int e2 = 0; e2 < 16; ++e2) {
                float v = prow[e2] + bv[e2];
                v = v > 0.f ? v : 0.f;
                u16 q = f2bf(v);
                if (e2 < 8) o0[e2] = (short)q; else o1[e2 - 8] = (short)q;
                pdot += bf2f(q) * wv[e2];
            }
            size_t off = (size_t)grow * 256 + rcol;
            *(short8*)(outp + off) = o0;
            *(short8*)(outp + off + 8) = o1;
            pdot += __shfl_xor(pdot, 1); pdot += __shfl_xor(pdot, 2);
            pdot += __shfl_xor(pdot, 4); pdot += __shfl_xor(pdot, 8);
            if ((lane & 15) == 0) t_out[grow] = pdot;
            __syncthreads();
        }
    } else {
        // relu(acc + bias) -> bf16 bounce -> coalesced atomh stores
        u16* Pu = (u16*)ldsbuf;         // [32][264] u16
        float bl0 = bias[(w * 2 + 0) * 16 + mr];
        float bl1 = bias[(w * 2 + 1) * 16 + mr];
#pragma unroll
        for (int mf = 0; mf < MF; ++mf)
#pragma unroll
            for (int r = 0; r < 4; ++r) {
                float v0 = acc[mf][0][r] + bl0; v0 = v0 > 0.f ? v0 : 0.f;
                float v1 = acc[mf][1][r] + bl1; v1 = v1 > 0.f ? v1 : 0.f;
                Pu[(mf * 16 + quad * 4 + r) * 264 + (w * 2 + 0) * 16 + mr] = f2bf(v0);
                Pu[(mf * 16 + quad * 4 + r) * 264 + (w * 2 + 1) * 16 + mr] = f2bf(v1);
            }
        __syncthreads();
        {
            const int rrow = tid >> 4;
            const int rcol = (tid & 15) * 16;
            size_t off = (size_t)(m0 + rrow) * 256 + rcol;
            *(short8*)(outp + off)     = *(const short8*)(Pu + rrow * 264 + rcol);
            *(short8*)(outp + off + 8) = *(const short8*)(Pu + rrow * 264 + rcol + 8);
        }

        // ---- fused second GEMM: hW = atomh(Pu) @ Bt2 (wta panel), K=256, barrier-free ----
        floatx4 acc2[2][2] = {};
        const u16* cp0 = Bt2 + (size_t)(w * 32 + mr) * 256 + quad * 8;
        const u16* cp1 = cp0 + (size_t)16 * 256;
#pragma unroll 2
        for (int ks = 0; ks < 8; ++ks) {
            const int k0 = ks * 32;
            short8 bf0 = *(const short8*)(cp0 + k0);
            short8 bf1 = *(const short8*)(cp1 + k0);
#pragma unroll
            for (int mf = 0; mf < 2; ++mf) {
                short8 af = *(const short8*)(Pu + (mf * 16 + mr) * 264 + k0 + quad * 8);
                acc2[mf][0] = MFMA16(af, bf0, acc2[mf][0]);
                acc2[mf][1] = MFMA16(af, bf1, acc2[mf][1]);
            }
        }
        __syncthreads();                // all Pu reads done before overwrite
#pragma unroll
        for (int mf = 0; mf < 2; ++mf)
#pragma unroll
            for (int jj = 0; jj < 2; ++jj)
#pragma unroll
                for (int r = 0; r < 4; ++r)
                    Pu[(mf * 16 + quad * 4 + r) * 264 + (w * 2 + jj) * 16 + mr] = f2bf(acc2[mf][jj][r]);
        __syncthreads();
        {
            const int rrow = tid >> 4;
            const int rcol = (tid & 15) * 16;
            size_t off = (size_t)(m0 + rrow) * 256 + rcol;
            *(short8*)(out2 + off)     = *(const short8*)(Pu + rrow * 264 + rcol);
            *(short8*)(out2 + off + 8) = *(const short8*)(Pu + rrow * 264 + rcol + 8);
        }
    }
}

// ================= fused molecule tail: scores+softmax+PV (+ wtb GEMM + final reduce) =================
// out[b,d] = (sum_a h[a,d] + sum_a relu((softmax(hW@h^T)@h)@W_b + b_b)[a,d]) / 32
// Eliminates zbuf/atth round-trips (134 MB) and atomh re-read (33.5 MB) vs 3-kernel tail.
#define HSTR 260
__global__ __launch_bounds__(256) void mol_attn2(const u16* __restrict__ atomh, const u16* __restrict__ hWg,
                                                 const u16* __restrict__ wtb, const float* __restrict__ bb,
                                                 float* __restrict__ out) {
    __shared__ float hs[32 * HSTR];     // 33280 B, f32 h
    __shared__ float P[32 * 33];        // 4224 B
    __shared__ u16 zl[32 * 264];        // 16896 B, bf16 z (wtb-GEMM A operand)
    __shared__ float hsum[256];         // col-sums of h
    __shared__ float attsum[256];       // col-sums of att_h
    const int t = threadIdx.x;
    const int b = blockIdx.x;
    const int lane = t & 63, quad = lane >> 4, mr = lane & 15, w = t >> 6;
    const u16* hbase = atomh + (size_t)b * 32 * 256;
    for (int e0 = t * 4; e0 < 8192; e0 += 1024) {
        int row = e0 >> 8, col = e0 & 255;
        ushort4 u = *(const ushort4*)(hbase + e0);
        floatx4 v; v.x = bf2f(u.x); v.y = bf2f(u.y); v.z = bf2f(u.z); v.w = bf2f(u.w);
        *(floatx4*)&hs[row * HSTR + col] = v;
    }
    __syncthreads();

    {   // scores: P[a][c] = hW[a] . h[c]
        int c = t & 31, a0 = t >> 5;
        const u16* hWb = hWg + (size_t)b * 32 * 256;
        for (int r = 0; r < 4; ++r) {
            int a = a0 + r * 8;
            const u16* hwrow = hWb + a * 256;
            float s = 0.f;
            for (int d = 0; d < 256; d += 4) {
                ushort4 u = *(const ushort4*)(hwrow + d);
                const float* hp = &hs[c * HSTR + d];
                s += bf2f(u.x) * hp[0] + bf2f(u.y) * hp[1] + bf2f(u.z) * hp[2] + bf2f(u.w) * hp[3];
            }
            P[a * 33 + c] = s;
        }
    }
    __syncthreads();
    if (t < 32) {   // row softmax
        float* prow = &P[t * 33];
        float mx = prow[0];
        for (int i = 1; i < 32; ++i) mx = fmaxf(mx, prow[i]);
        float den = 0.f;
        for (int i = 0; i < 32; ++i) { float ev = __expf(prow[i] - mx); prow[i] = ev; den += ev; }
        float inv = 1.f / den;
        for (int i = 0; i < 32; ++i) prow[i] *= inv;
    }
    __syncthreads();

    {   // PV: z[a] = sum_c P[a][c] h[c]  -> bf16 zl ; also h col-sums
        int a = t >> 3, q = t & 7;
        floatx4 acc8[8];
#pragma unroll
        for (int i = 0; i < 8; ++i) acc8[i] = (floatx4){0.f, 0.f, 0.f, 0.f};
        const float* prow = &P[a * 33];
        for (int cc = 0; cc < 32; ++cc) {
            float p = prow[cc];
            const float* hrow = &hs[cc * HSTR + q * 4];
#pragma unroll
            for (int i = 0; i < 8; ++i) {
                floatx4 hv = *(const floatx4*)(hrow + i * 32);
                acc8[i] += p * hv;
            }
        }
        u16* zrow = zl + a * 264 + q * 4;
#pragma unroll
        for (int i = 0; i < 8; ++i) {
            ushort4 o;
            o.x = f2bf(acc8[i].x); o.y = f2bf(acc8[i].y); o.z = f2bf(acc8[i].z); o.w = f2bf(acc8[i].w);
            *(ushort4*)(zrow + i * 32) = o;
        }
        // h column sums (hs stable): thread t owns column t
        float s = 0.f;
        for (int aa = 0; aa < 32; ++aa) s += hs[aa * HSTR + t];
        hsum[t] = s;
    }
    __syncthreads();

    {   // wtb GEMM: att_pre = zl @ wtb^T ; atth = relu(att_pre + bb); column-reduce over 32 atoms
        floatx4 acc2[2][4] = {};
        const u16* bp[4];
        float blw[4];
#pragma unroll
        for (int jj = 0; jj < 4; ++jj) {
            int col = w * 64 + jj * 16 + mr;
            bp[jj] = wtb + (size_t)col * 256 + quad * 8;
            blw[jj] = bb[col];
        }
#pragma unroll 2
        for (int ks = 0; ks < 8; ++ks) {
            const int k0 = ks * 32;
            short8 bf0 = *(const short8*)(bp[0] + k0);
            short8 bf1 = *(const short8*)(bp[1] + k0);
            short8 bf2v = *(const short8*)(bp[2] + k0);
            short8 bf3 = *(const short8*)(bp[3] + k0);
#pragma unroll
            for (int mf = 0; mf < 2; ++mf) {
                short8 af = *(const short8*)(zl + (mf * 16 + mr) * 264 + k0 + quad * 8);
                acc2[mf][0] = MFMA16(af, bf0, acc2[mf][0]);
                acc2[mf][1] = MFMA16(af, bf1, acc2[mf][1]);
                acc2[mf][2] = MFMA16(af, bf2v, acc2[mf][2]);
                acc2[mf][3] = MFMA16(af, bf3, acc2[mf][3]);
            }
        }
#pragma unroll
        for (int jj = 0; jj < 4; ++jj) {
            float s = 0.f;
#pragma unroll
            for (int mf = 0; mf < 2; ++mf)
#pragma unroll
                for (int r = 0; r < 4; ++r) {
                    float v = acc2[mf][jj][r] + blw[jj];
                    s += (v > 0.f ? v : 0.f);
                }
            s += __shfl_xor(s, 16);
            s += __shfl_xor(s, 32);
            if (quad == 0) attsum[w * 64 + jj * 16 + mr] = s;
        }
    }
    __syncthreads();
    out[(size_t)b * 256 + t] = (hsum[t] + attsum[t]) * 0.03125f;
}

// ================= workspace layout (bytes) =================
#define O_FBP      ((size_t)0)                        // 41,943,040  (atomh home)
#define O_BINPUT   ((size_t)41943040)                 // 67,108,864  binput -> later hW (+0)
#define O_MSGA     ((size_t)109051904)                // 67,108,864  msgA
#define O_MSGB     ((size_t)176160768)                // 67,108,864  msgB (msg ping-pong)
#define O_W        ((size_t)243269632)
#define O_WTI      (O_W)                              // 81,920
#define O_WTH      (O_W + 81920)                      // 131,072
#define O_WTO      (O_W + 212992)                     // 212,992
#define O_WTA      (O_W + 425984)                     // 131,072
#define O_WTB      (O_W + 557056)                     // 131,072
#define WS_NEED    ((size_t)243957760)

extern "C" void kernel_launch(void* const* d_in, const int* in_sizes, int n_in,
                              void* d_out, int out_size, void* d_ws, size_t ws_size,
                              hipStream_t stream) {
    const float* fatoms = (const float*)d_in[0];
    const float* fbonds = (const float*)d_in[1];
    const int*   agraph = (const int*)d_in[2];
    const int*   bgraph = (const int*)d_in[3];
    const float* W_i    = (const float*)d_in[5];
    const float* W_h    = (const float*)d_in[6];
    const float* W_o_w  = (const float*)d_in[7];
    const float* W_o_b  = (const float*)d_in[8];
    const float* W_a    = (const float*)d_in[9];
    const float* W_b_w  = (const float*)d_in[10];
    const float* W_b_b  = (const float*)d_in[11];
    const float* W_ma1  = (const float*)d_in[12];
    float* out = (float*)d_out;

    if (ws_size < WS_NEED) return;

    char* ws = (char*)d_ws;
    u16* binput  = (u16*)(ws + O_BINPUT);
    u16* msgA    = (u16*)(ws + O_MSGA);
    u16* msgB    = (u16*)(ws + O_MSGB);
    u16* wti     = (u16*)(ws + O_WTI);
    u16* wth     = (u16*)(ws + O_WTH);
    u16* wto     = (u16*)(ws + O_WTO);
    u16* wta     = (u16*)(ws + O_WTA);
    u16* wtb     = (u16*)(ws + O_WTB);
    // aliases (dead-buffer reuse)
    u16* atomh   = (u16*)(ws + O_FBP);
    u16* hW      = (u16*)(ws + O_BINPUT);   // binput dead after fused iter 3
    // t score ping-pong lives in d_out (overwritten by mol_attn2 at the end)
    float* tA = (float*)d_out;
    float* tB = tA + E_BONDS;

    // prep (weights only; fbonds consumed raw by the F32A GEMM)
    prep_wt<<<160, 256, 0, stream>>>(W_i, wti, 157, KPAD_I);
    prep_wt<<<256, 256, 0, stream>>>(W_h, wth, 256, 256);
    prep_wo<<<416, 256, 0, stream>>>(W_o_w, wto);
    prep_wt<<<256, 256, 0, stream>>>(W_a, wta, 256, 256);
    prep_wt<<<256, 256, 0, stream>>>(W_b_w, wtb, 256, 256);

    // binput = fbonds @ W_i (pre-relu stored) ; t0 = relu(binput) . Wma  — A staged from raw f32
    gemm256<1, false, true><<<1024, 512, 0, stream>>>(nullptr, wti, binput, nullptr, W_ma1, tA, KPAD_I, fbonds);

    // fused message iterations: gather is the A-stage of the W_h GEMM (Mp never materialized)
    fused_gg<1><<<E_BONDS / 64, 512, 0, stream>>>(binput, wth, bgraph, tA, binput, nullptr, nullptr, W_ma1, msgA, tB, nullptr, nullptr);
    fused_gg<0><<<E_BONDS / 64, 512, 0, stream>>>(msgA,   wth, bgraph, tB, binput, nullptr, nullptr, W_ma1, msgB, tA, nullptr, nullptr);
    fused_gg<0><<<E_BONDS / 64, 512, 0, stream>>>(msgB,   wth, bgraph, tA, binput, nullptr, nullptr, W_ma1, msgA, tB, nullptr, nullptr);

    // fused atom stage: agraph-gather + fatoms tail -> atomh = relu(.@W_o+b) ; + fused hW = atomh@W_a
    fused_gg<2><<<N_ATOMS_C / 32, 512, 0, stream>>>(msgA, wto, agraph, nullptr, nullptr, fatoms, W_o_b, nullptr, atomh, nullptr, wta, hW);

    // fused molecule tail: scores + softmax + PV + wtb GEMM + final reduce
    mol_attn2<<<N_MOLS, 256, 0, stream>>>(atomh, hW, wtb, W_b_b, out);
}

// Round 10
// 623.926 us; speedup vs baseline: 1.0870x; 1.0870x over previous
//
#include <hip/hip_runtime.h>

typedef unsigned short u16;
typedef __attribute__((ext_vector_type(8))) short short8;
typedef __attribute__((ext_vector_type(4))) float floatx4;
typedef __attribute__((ext_vector_type(4), aligned(4))) float floatx4u;   // unaligned-safe vector load

// ---------- bf16 helpers (RNE) ----------
__device__ __forceinline__ float bf2f(u16 u) {
    return __uint_as_float(((unsigned int)u) << 16);
}
__device__ __forceinline__ u16 f2bf(float f) {
    unsigned int i = __float_as_uint(f);
    unsigned int r = i + 0x7FFFu + ((i >> 16) & 1u);
    return (u16)(r >> 16);
}
// relu on two packed bf16 (zero halves with sign bit set)
__device__ __forceinline__ unsigned int relu2(unsigned int x) {
    unsigned int m = (((x >> 15) & 1u) * 0x0000FFFFu) | ((x >> 31) * 0xFFFF0000u);
    return x & ~m;
}

// ---------- async global->LDS (16B per lane, wave-uniform LDS base) ----------
typedef __attribute__((address_space(3))) void lds_void;
typedef const __attribute__((address_space(1))) void g_void;
__device__ __forceinline__ void async_copy16(const void* g, void* l) {
    __builtin_amdgcn_global_load_lds((g_void*)g, (lds_void*)l, 16, 0, 0);
}

__device__ __forceinline__ void acc_bf8(float* a8, uint4 u, float wj) {
    a8[0] += wj * __uint_as_float(u.x << 16);
    a8[1] += wj * __uint_as_float(u.x & 0xffff0000u);
    a8[2] += wj * __uint_as_float(u.y << 16);
    a8[3] += wj * __uint_as_float(u.y & 0xffff0000u);
    a8[4] += wj * __uint_as_float(u.z << 16);
    a8[5] += wj * __uint_as_float(u.z & 0xffff0000u);
    a8[6] += wj * __uint_as_float(u.w << 16);
    a8[7] += wj * __uint_as_float(u.w & 0xffff0000u);
}

#define MFMA16(a, b, c) __builtin_amdgcn_mfma_f32_16x16x32_bf16(a, b, c, 0, 0, 0)

// ================= problem constants =================
#define E_BONDS 131072
#define N_ATOMS_C 65536
#define KPAD_I 160     // 157 padded
#define KPAD_O 416     // 399 padded
#define N_MOLS 2048

// ================= prep kernels =================
// W [K,256] f32 -> Wt [256, Kpad] bf16 (transposed, zero-padded)
__global__ __launch_bounds__(256) void prep_wt(const float* __restrict__ W, u16* __restrict__ Wt, int K, int Kpad) {
    int idx = blockIdx.x * 256 + threadIdx.x;           // 256*Kpad total
    int n = idx / Kpad;
    int k = idx - n * Kpad;
    float v = (k < K) ? W[(size_t)k * 256 + n] : 0.f;
    Wt[idx] = f2bf(v);
}

// W_o_w [399,256] -> reordered transposed [256,416]
__global__ __launch_bounds__(256) void prep_wo(const float* __restrict__ W, u16* __restrict__ Wt) {
    int idx = blockIdx.x * 256 + threadIdx.x;           // 256*416 total
    int n = idx / KPAD_O;
    int k = idx - n * KPAD_O;
    float v = 0.f;
    if (k < 256)      v = W[(size_t)(143 + k) * 256 + n];
    else if (k < 399) v = W[(size_t)(k - 256) * 256 + n];
    Wt[idx] = f2bf(v);
}

// ================= MFMA GEMM, N=256 full width: C[M,256] = epi(A[M,K] @ Bt[256,K]^T) =================
// EPI: 0 plain->out ; 1 out=pre, tout=relu(pre).wma score ; 3 out=relu(acc+bias)
// RELUA: apply bf16-relu to A during staging. F32A: A staged from raw f32 rows (width 157, fbonds),
//   coalesced mapping row=tid>>2, kb=tid&3 (R7 lesson: row=tid&127 was latency-bound, 104us).
// 512 thr = 8 waves x 16 rows; M-tile 128; acc[16] = 64 AGPR/wave.
template <int EPI, bool RELUA, bool F32A>
__global__ __launch_bounds__(512, 3) void gemm256(
    const u16* __restrict__ A, const u16* __restrict__ Bt,
    u16* __restrict__ out,
    const float* __restrict__ bias, const float* __restrict__ wma,
    float* __restrict__ tout, int K, const float* __restrict__ Af32)
{
    __shared__ char ldsbuf[33792];     // stage: Al 8192 + Bl 16384 = 24576 ; epi: 8 waves x 4224
    u16* Al = (u16*)ldsbuf;            // [kb=4][row=128][8]
    u16* Bl = (u16*)(ldsbuf + 8192);   // [kb=4][n=256][8]

    const int tid = threadIdx.x;
    const int w = tid >> 6, lane = tid & 63;
    const int quad = lane >> 4, mr = lane & 15;
    const int m0 = blockIdx.x * 128;

    floatx4 acc[16] = {};

    const u16* Ag = F32A ? nullptr : (A + (size_t)(m0 + (tid & 127)) * K + ((tid >> 7) << 3));
    const float* Af = F32A ? (Af32 + (size_t)(m0 + (tid >> 2)) * 157) : nullptr;

    for (int k0 = 0; k0 < K; k0 += 32) {
        if (F32A) {
            const int kb = tid & 3;
            const int cb = k0 + kb * 8;
            short8 xv;
            if (cb + 8 <= 157) {
                floatx4u v0 = *(const floatx4u*)(Af + cb);
                floatx4u v1 = *(const floatx4u*)(Af + cb + 4);
                xv[0] = (short)f2bf(v0.x); xv[1] = (short)f2bf(v0.y);
                xv[2] = (short)f2bf(v0.z); xv[3] = (short)f2bf(v0.w);
                xv[4] = (short)f2bf(v1.x); xv[5] = (short)f2bf(v1.y);
                xv[6] = (short)f2bf(v1.z); xv[7] = (short)f2bf(v1.w);
            } else {
#pragma unroll
                for (int e = 0; e < 8; ++e) {
                    int c = cb + e;
                    float v = (c < 157) ? Af[c] : 0.f;
                    xv[e] = (short)f2bf(v);
                }
            }
            *(short8*)(Al + ((kb << 7) + (tid >> 2)) * 8) = xv;
        } else if (RELUA) {
            uint4 x = *(const uint4*)(Ag + k0);
            x.x = relu2(x.x); x.y = relu2(x.y); x.z = relu2(x.z); x.w = relu2(x.w);
            *(uint4*)(Al + tid * 8) = x;
        } else {
            async_copy16(Ag + k0, Al + tid * 8);
        }
#pragma unroll
        for (int i = 0; i < 2; ++i) {
            int c = tid + i * 512;
            async_copy16(Bt + (size_t)(c & 255) * K + k0 + ((c >> 8) << 3), Bl + c * 8);
        }
        __syncthreads();

        short8 af = *(const short8*)(Al + quad * 1024 + (w * 16 + mr) * 8);
#pragma unroll
        for (int j = 0; j < 16; ++j) {
            short8 bf = *(const short8*)(Bl + quad * 2048 + (j * 16 + mr) * 8);
            acc[j] = MFMA16(af, bf, acc[j]);
        }
        __syncthreads();
    }

    // ---- coalesced epilogue: two 8-row passes through a wave-private LDS slice ----
    u16* slice = (u16*)ldsbuf + w * 2112;       // 8 rows x 264 u16 = 4224 B
    const int lhalf = lane >> 5;
    const int lcol = (lane & 31) * 8;
    float wmal8[8];
    if (EPI == 1) {
#pragma unroll
        for (int e = 0; e < 8; ++e) wmal8[e] = wma[lcol + e];
    }
    float bl16[16];
    if (EPI == 3) {
#pragma unroll
        for (int j = 0; j < 16; ++j) bl16[j] = bias[j * 16 + mr];
    }

#pragma unroll
    for (int p = 0; p < 2; ++p) {
        if ((quad >> 1) == p) {
            int lr = (quad & 1) * 4;
#pragma unroll
            for (int j = 0; j < 16; ++j)
#pragma unroll
                for (int r = 0; r < 4; ++r) {
                    float v = acc[j][r];
                    if (EPI == 3) { v += bl16[j]; v = v > 0.f ? v : 0.f; }
                    slice[(lr + r) * 264 + j * 16 + mr] = f2bf(v);
                }
        }
        __syncthreads();
#pragma unroll
        for (int round = 0; round < 4; ++round) {
            int rowl = round * 2 + lhalf;
            int row = m0 + w * 16 + p * 8 + rowl;
            size_t off = (size_t)row * 256 + lcol;
            short8 pv = *(const short8*)(slice + rowl * 264 + lcol);
            if (EPI == 0 || EPI == 3) {
                *(short8*)(out + off) = pv;
            } else {   // EPI 1: store pre; score from relu(pre)
                *(short8*)(out + off) = pv;
                float pdot = 0.f;
#pragma unroll
                for (int e = 0; e < 8; ++e) {
                    u16 u = (u16)pv[e];
                    u = (u & 0x8000u) ? (u16)0 : u;
                    pdot += bf2f(u) * wmal8[e];
                }
                pdot += __shfl_xor(pdot, 1); pdot += __shfl_xor(pdot, 2);
                pdot += __shfl_xor(pdot, 4); pdot += __shfl_xor(pdot, 8);
                pdot += __shfl_xor(pdot, 16);
                if ((lane & 31) == 0) tout[row] = pdot;
            }
        }
        __syncthreads();
    }
}

// ================= fused gather + GEMM, barrier-free K-loop (R2 geometry) =================
// Linearity: (sum_j w_j * msg[b_j]) @ W == sum_j w_j * (msg[b_j] @ W).
// 512 thr = 8 waves, MT=64. B (L2-resident weight panel) read per-wave directly from global
// as MFMA fragments -> no LDS B staging, no K-loop barriers. acc[MF][2] = 32 VGPR.
// NOTE (R6): nontemporal hints HURT (NT stores lose L2 write-combining: WRITE 66->108MB). Plain ops.
// MODE 0: iter — A[r] = sum_j softmax(t[b_j]) * msg_prev[b_j]; epi: msg = relu(binput + acc), t_out = msg.wma
// MODE 1: iter1 — like MODE 0 but gathers binput rows with relu-on-load (msg0 = relu(binput))
// MODE 2: atom — A[r] = [sum_j msg[a_j] | fatoms_row | 0-pad], K=416; epi: atomh = relu(acc + bias);
//         then SECOND GEMM from the atomh LDS bounce: hW = atomh @ Bt2 (wta panel) -> out2.
template <int MODE>
__global__ __launch_bounds__(512, 6) void fused_gg(
    const u16* src, const u16* __restrict__ Bt, const int* __restrict__ graph,
    const float* __restrict__ t_in, const u16* __restrict__ binput,
    const float* __restrict__ fatoms, const float* __restrict__ bias,
    const float* __restrict__ wma, u16* __restrict__ outp, float* __restrict__ t_out,
    const u16* __restrict__ Bt2, u16* __restrict__ out2)
{
    constexpr int MT = (MODE == 2) ? 32 : 64;       // M tile (rows)
    constexpr int KK = (MODE == 2) ? 416 : 256;     // K
    constexpr int KP = KK + 8;                      // padded A stride (u16)
    constexpr int MF = MT / 16;                     // m-fragments per wave (4 or 2)
    constexpr int LDSB = (MODE == 2) ? (32 * 424 * 2) : (32 * 268 * 4);   // 27136 / 34304

    __shared__ __align__(16) char ldsbuf[LDSB];
    u16* As = (u16*)ldsbuf;             // [MT][KP]

    const int tid = threadIdx.x;
    const int w = tid >> 6, lane = tid & 63;
    const int quad = lane >> 4, mr = lane & 15;
    const int hw = tid >> 5, l32 = tid & 31;
    const int m0 = blockIdx.x * MT;

    // ---------- gather phase: build A tile in LDS (half-wave per row, 16 half-waves) ----------
    for (int it = 0; it < MT / 16; ++it) {
        const int r = it * 16 + hw;
        const int e = m0 + r;
        const int* bg = graph + (size_t)e * 6;
        int2 b01 = *(const int2*)bg;
        int2 b23 = *(const int2*)(bg + 2);
        int2 b45 = *(const int2*)(bg + 4);
        int b[6] = {b01.x, b01.y, b23.x, b23.y, b45.x, b45.y};

        float wg[6];
        if (MODE != 2) {
            float s[6];
#pragma unroll
            for (int j = 0; j < 6; ++j) s[j] = t_in[b[j]];
            float mx = fmaxf(fmaxf(fmaxf(s[0], s[1]), fmaxf(s[2], s[3])), fmaxf(s[4], s[5]));
            float den = 0.f;
#pragma unroll
            for (int j = 0; j < 6; ++j) { wg[j] = __expf(s[j] - mx); den += wg[j]; }
            float inv = 1.f / den;
#pragma unroll
            for (int j = 0; j < 6; ++j) wg[j] *= inv;
        }

        float a8[8] = {};
#pragma unroll
        for (int j = 0; j < 6; ++j) {
            uint4 u = *(const uint4*)(src + (size_t)b[j] * 256 + l32 * 8);
            if (MODE == 1) { u.x = relu2(u.x); u.y = relu2(u.y); u.z = relu2(u.z); u.w = relu2(u.w); }
            acc_bf8(a8, u, (MODE == 2) ? 1.f : wg[j]);
        }
        short8 mv;
#pragma unroll
        for (int k = 0; k < 8; ++k) mv[k] = (short)f2bf(a8[k]);
        *(short8*)(As + r * KP + l32 * 8) = mv;

        if (MODE == 2) {
            const float* frow = fatoms + (size_t)e * 143;
#pragma unroll
            for (int i = 0; i < 5; ++i) {
                int c = l32 + i * 32;
                As[r * KP + 256 + c] = (c < 143) ? f2bf(frow[c]) : (u16)0;
            }
        }
    }
    __syncthreads();

    // ---------- barrier-free K-loop: B frags straight from global (L2-hit), A from LDS ----------
    floatx4 acc[MF][2] = {};
    const u16* bp0 = Bt + (size_t)(w * 32 + mr) * KK + quad * 8;
    const u16* bp1 = bp0 + (size_t)16 * KK;
#pragma unroll 2
    for (int ks = 0; ks < KK / 32; ++ks) {
        const int k0 = ks * 32;
        short8 bf0 = *(const short8*)(bp0 + k0);
        short8 bf1 = *(const short8*)(bp1 + k0);
#pragma unroll
        for (int mf = 0; mf < MF; ++mf) {
            short8 af = *(const short8*)(As + (mf * 16 + mr) * KP + k0 + quad * 8);
            acc[mf][0] = MFMA16(af, bf0, acc[mf][0]);
            acc[mf][1] = MFMA16(af, bf1, acc[mf][1]);
        }
    }
    __syncthreads();                    // all As reads done before bounce overwrite

    // ---------- epilogue ----------
    if (MODE != 2) {
        // f32 bounce (keeps acc full precision through binput add) in two 32-row passes
        float* Pf = (float*)ldsbuf;     // [32][268] f32
        const int rrow = tid >> 4;      // 0..31
        const int rcol = (tid & 15) * 16;
        float wv[16];
#pragma unroll
        for (int e2 = 0; e2 < 16; ++e2) wv[e2] = wma[rcol + e2];

#pragma unroll
        for (int p = 0; p < 2; ++p) {
#pragma unroll
            for (int mi = 0; mi < 2; ++mi) {
#pragma unroll
                for (int jj = 0; jj < 2; ++jj)
#pragma unroll
                    for (int r = 0; r < 4; ++r)
                        Pf[(mi * 16 + quad * 4 + r) * 268 + (w * 2 + jj) * 16 + mr] = acc[p * 2 + mi][jj][r];
            }
            __syncthreads();
            const int grow = m0 + p * 32 + rrow;
            const u16* brow = binput + (size_t)grow * 256 + rcol;
            uint4 bu0 = *(const uint4*)brow;
            uint4 bu1 = *(const uint4*)(brow + 8);
            float bv[16] = {
                __uint_as_float(bu0.x << 16), __uint_as_float(bu0.x & 0xffff0000u),
                __uint_as_float(bu0.y << 16), __uint_as_float(bu0.y & 0xffff0000u),
                __uint_as_float(bu0.z << 16), __uint_as_float(bu0.z & 0xffff0000u),
                __uint_as_float(bu0.w << 16), __uint_as_float(bu0.w & 0xffff0000u),
                __uint_as_float(bu1.x << 16), __uint_as_float(bu1.x & 0xffff0000u),
                __uint_as_float(bu1.y << 16), __uint_as_float(bu1.y & 0xffff0000u),
                __uint_as_float(bu1.z << 16), __uint_as_float(bu1.z & 0xffff0000u),
                __uint_as_float(bu1.w << 16), __uint_as_float(bu1.w & 0xffff0000u)};
            const float* prow = Pf + rrow * 268 + rcol;
            float pdot = 0.f;
            short8 o0, o1;
#pragma unroll
            for (int e2 = 0; e2 < 16; ++e2) {
                float v = prow[e2] + bv[e2];
                v = v > 0.f ? v : 0.f;
                u16 q = f2bf(v);
                if (e2 < 8) o0[e2] = (short)q; else o1[e2 - 8] = (short)q;
                pdot += bf2f(q) * wv[e2];
            }
            size_t off = (size_t)grow * 256 + rcol;
            *(short8*)(outp + off) = o0;
            *(short8*)(outp + off + 8) = o1;
            pdot += __shfl_xor(pdot, 1); pdot += __shfl_xor(pdot, 2);
            pdot += __shfl_xor(pdot, 4); pdot += __shfl_xor(pdot, 8);
            if ((lane & 15) == 0) t_out[grow] = pdot;
            __syncthreads();
        }
    } else {
        // relu(acc + bias) -> bf16 bounce -> coalesced atomh stores
        u16* Pu = (u16*)ldsbuf;         // [32][264] u16
        float bl0 = bias[(w * 2 + 0) * 16 + mr];
        float bl1 = bias[(w * 2 + 1) * 16 + mr];
#pragma unroll
        for (int mf = 0; mf < MF; ++mf)
#pragma unroll
            for (int r = 0; r < 4; ++r) {
                float v0 = acc[mf][0][r] + bl0; v0 = v0 > 0.f ? v0 : 0.f;
                float v1 = acc[mf][1][r] + bl1; v1 = v1 > 0.f ? v1 : 0.f;
                Pu[(mf * 16 + quad * 4 + r) * 264 + (w * 2 + 0) * 16 + mr] = f2bf(v0);
                Pu[(mf * 16 + quad * 4 + r) * 264 + (w * 2 + 1) * 16 + mr] = f2bf(v1);
            }
        __syncthreads();
        {
            const int rrow = tid >> 4;
            const int rcol = (tid & 15) * 16;
            size_t off = (size_t)(m0 + rrow) * 256 + rcol;
            *(short8*)(outp + off)     = *(const short8*)(Pu + rrow * 264 + rcol);
            *(short8*)(outp + off + 8) = *(const short8*)(Pu + rrow * 264 + rcol + 8);
        }

        // ---- fused second GEMM: hW = atomh(Pu) @ Bt2 (wta panel), K=256, barrier-free ----
        floatx4 acc2[2][2] = {};
        const u16* cp0 = Bt2 + (size_t)(w * 32 + mr) * 256 + quad * 8;
        const u16* cp1 = cp0 + (size_t)16 * 256;
#pragma unroll 2
        for (int ks = 0; ks < 8; ++ks) {
            const int k0 = ks * 32;
            short8 bf0 = *(const short8*)(cp0 + k0);
            short8 bf1 = *(const short8*)(cp1 + k0);
#pragma unroll
            for (int mf = 0; mf < 2; ++mf) {
                short8 af = *(const short8*)(Pu + (mf * 16 + mr) * 264 + k0 + quad * 8);
                acc2[mf][0] = MFMA16(af, bf0, acc2[mf][0]);
                acc2[mf][1] = MFMA16(af, bf1, acc2[mf][1]);
            }
        }
        __syncthreads();                // all Pu reads done before overwrite
#pragma unroll
        for (int mf = 0; mf < 2; ++mf)
#pragma unroll
            for (int jj = 0; jj < 2; ++jj)
#pragma unroll
                for (int r = 0; r < 4; ++r)
                    Pu[(mf * 16 + quad * 4 + r) * 264 + (w * 2 + jj) * 16 + mr] = f2bf(acc2[mf][jj][r]);
        __syncthreads();
        {
            const int rrow = tid >> 4;
            const int rcol = (tid & 15) * 16;
            size_t off = (size_t)(m0 + rrow) * 256 + rcol;
            *(short8*)(out2 + off)     = *(const short8*)(Pu + rrow * 264 + rcol);
            *(short8*)(out2 + off + 8) = *(const short8*)(Pu + rrow * 264 + rcol + 8);
        }
    }
}

// ================= fused molecule tail v2: MFMA scores + softmax + PV + wtb GEMM + reduce =================
// R9 lesson: v1 was 138us @ 22% occupancy — 56.8KB LDS (2 blocks/CU) + scalar 32x32x256 scores.
// v2: h kept bf16 in LDS (16.9KB, no f32 conversion) -> 40KB total -> 4 blocks/CU; scores via MFMA
// (8 mfma/wave replaces 1024 scalar MACs/thread). P stays f32; PV scalar f32 (numerics preserved).
__global__ __launch_bounds__(256) void mol_attn2(const u16* __restrict__ atomh, const u16* __restrict__ hWg,
                                                 const u16* __restrict__ wtb, const float* __restrict__ bb,
                                                 float* __restrict__ out) {
    __shared__ u16 hs[32 * 264];        // 16896 B, bf16 h
    __shared__ float P[32 * 33];        // 4224 B
    __shared__ u16 zl[32 * 264];        // 16896 B, bf16 z (wtb-GEMM A operand)
    __shared__ float hsum[256];         // col-sums of h
    __shared__ float attsum[256];       // col-sums of att_h
    const int t = threadIdx.x;
    const int b = blockIdx.x;
    const int lane = t & 63, quad = lane >> 4, mr = lane & 15, w = t >> 6;
    const u16* hbase = atomh + (size_t)b * 32 * 256;
#pragma unroll
    for (int it = 0; it < 4; ++it) {
        int ci = t + it * 256;                  // 1024 chunks of 8 bf16
        int row = ci >> 5, col = (ci & 31) * 8;
        *(short8*)(hs + row * 264 + col) = *(const short8*)(hbase + ci * 8);
    }
    __syncthreads();

    {   // scores via MFMA: P[a][c] = hW[a] . h[c]; wave w -> tile a0=(w&1)*16, c0=(w>>1)*16
        const int a0 = (w & 1) * 16, c0 = (w >> 1) * 16;
        floatx4 pac = {0.f, 0.f, 0.f, 0.f};
        const u16* hwrow = hWg + (size_t)b * 8192 + (size_t)(a0 + mr) * 256 + quad * 8;
        const u16* hrow = hs + (c0 + mr) * 264 + quad * 8;
#pragma unroll
        for (int ks = 0; ks < 8; ++ks) {
            short8 af = *(const short8*)(hwrow + ks * 32);
            short8 bf = *(const short8*)(hrow + ks * 32);
            pac = MFMA16(af, bf, pac);
        }
#pragma unroll
        for (int r = 0; r < 4; ++r)
            P[(a0 + quad * 4 + r) * 33 + c0 + mr] = pac[r];
    }
    __syncthreads();
    if (t < 32) {   // row softmax (short serial: 32 elems)
        float* prow = &P[t * 33];
        float mx = prow[0];
        for (int i = 1; i < 32; ++i) mx = fmaxf(mx, prow[i]);
        float den = 0.f;
        for (int i = 0; i < 32; ++i) { float ev = __expf(prow[i] - mx); prow[i] = ev; den += ev; }
        float inv = 1.f / den;
        for (int i = 0; i < 32; ++i) prow[i] *= inv;
    }
    __syncthreads();

    {   // PV: z[a] = sum_c P[a][c] h[c] (P f32, h bf16) -> bf16 zl ; also h col-sums
        int a = t >> 3, q = t & 7;
        floatx4 acc8[8];
#pragma unroll
        for (int i = 0; i < 8; ++i) acc8[i] = (floatx4){0.f, 0.f, 0.f, 0.f};
        const float* prow = &P[a * 33];
        for (int cc = 0; cc < 32; ++cc) {
            float p = prow[cc];
            const u16* hrow = hs + cc * 264 + q * 4;
#pragma unroll
            for (int i = 0; i < 8; ++i) {
                ushort4 hv = *(const ushort4*)(hrow + i * 32);
                acc8[i].x += p * bf2f(hv.x);
                acc8[i].y += p * bf2f(hv.y);
                acc8[i].z += p * bf2f(hv.z);
                acc8[i].w += p * bf2f(hv.w);
            }
        }
        u16* zrow = zl + a * 264 + q * 4;
#pragma unroll
        for (int i = 0; i < 8; ++i) {
            ushort4 o;
            o.x = f2bf(acc8[i].x); o.y = f2bf(acc8[i].y); o.z = f2bf(acc8[i].z); o.w = f2bf(acc8[i].w);
            *(ushort4*)(zrow + i * 32) = o;
        }
        // h column sums: thread t owns column t
        float s = 0.f;
        for (int aa = 0; aa < 32; ++aa) s += bf2f(hs[aa * 264 + t]);
        hsum[t] = s;
    }
    __syncthreads();

    {   // wtb GEMM: att_pre = zl @ wtb^T ; atth = relu(att_pre + bb); column-reduce over 32 atoms
        floatx4 acc2[2][4] = {};
        const u16* bp[4];
        float blw[4];
#pragma unroll
        for (int jj = 0; jj < 4; ++jj) {
            int col = w * 64 + jj * 16 + mr;
            bp[jj] = wtb + (size_t)col * 256 + quad * 8;
            blw[jj] = bb[col];
        }
#pragma unroll 2
        for (int ks = 0; ks < 8; ++ks) {
            const int k0 = ks * 32;
            short8 bf0 = *(const short8*)(bp[0] + k0);
            short8 bf1 = *(const short8*)(bp[1] + k0);
            short8 bf2v = *(const short8*)(bp[2] + k0);
            short8 bf3 = *(const short8*)(bp[3] + k0);
#pragma unroll
            for (int mf = 0; mf < 2; ++mf) {
                short8 af = *(const short8*)(zl + (mf * 16 + mr) * 264 + k0 + quad * 8);
                acc2[mf][0] = MFMA16(af, bf0, acc2[mf][0]);
                acc2[mf][1] = MFMA16(af, bf1, acc2[mf][1]);
                acc2[mf][2] = MFMA16(af, bf2v, acc2[mf][2]);
                acc2[mf][3] = MFMA16(af, bf3, acc2[mf][3]);
            }
        }
#pragma unroll
        for (int jj = 0; jj < 4; ++jj) {
            float s = 0.f;
#pragma unroll
            for (int mf = 0; mf < 2; ++mf)
#pragma unroll
                for (int r = 0; r < 4; ++r) {
                    float v = acc2[mf][jj][r] + blw[jj];
                    s += (v > 0.f ? v : 0.f);
                }
            s += __shfl_xor(s, 16);
            s += __shfl_xor(s, 32);
            if (quad == 0) attsum[w * 64 + jj * 16 + mr] = s;
        }
    }
    __syncthreads();
    out[(size_t)b * 256 + t] = (hsum[t] + attsum[t]) * 0.03125f;
}

// ================= workspace layout (bytes) =================
#define O_FBP      ((size_t)0)                        // 41,943,040  (atomh home)
#define O_BINPUT   ((size_t)41943040)                 // 67,108,864  binput -> later hW (+0)
#define O_MSGA     ((size_t)109051904)                // 67,108,864  msgA
#define O_MSGB     ((size_t)176160768)                // 67,108,864  msgB (msg ping-pong)
#define O_W        ((size_t)243269632)
#define O_WTI      (O_W)                              // 81,920
#define O_WTH      (O_W + 81920)                      // 131,072
#define O_WTO      (O_W + 212992)                     // 212,992
#define O_WTA      (O_W + 425984)                     // 131,072
#define O_WTB      (O_W + 557056)                     // 131,072
#define WS_NEED    ((size_t)243957760)

extern "C" void kernel_launch(void* const* d_in, const int* in_sizes, int n_in,
                              void* d_out, int out_size, void* d_ws, size_t ws_size,
                              hipStream_t stream) {
    const float* fatoms = (const float*)d_in[0];
    const float* fbonds = (const float*)d_in[1];
    const int*   agraph = (const int*)d_in[2];
    const int*   bgraph = (const int*)d_in[3];
    const float* W_i    = (const float*)d_in[5];
    const float* W_h    = (const float*)d_in[6];
    const float* W_o_w  = (const float*)d_in[7];
    const float* W_o_b  = (const float*)d_in[8];
    const float* W_a    = (const float*)d_in[9];
    const float* W_b_w  = (const float*)d_in[10];
    const float* W_b_b  = (const float*)d_in[11];
    const float* W_ma1  = (const float*)d_in[12];
    float* out = (float*)d_out;

    if (ws_size < WS_NEED) return;

    char* ws = (char*)d_ws;
    u16* binput  = (u16*)(ws + O_BINPUT);
    u16* msgA    = (u16*)(ws + O_MSGA);
    u16* msgB    = (u16*)(ws + O_MSGB);
    u16* wti     = (u16*)(ws + O_WTI);
    u16* wth     = (u16*)(ws + O_WTH);
    u16* wto     = (u16*)(ws + O_WTO);
    u16* wta     = (u16*)(ws + O_WTA);
    u16* wtb     = (u16*)(ws + O_WTB);
    // aliases (dead-buffer reuse)
    u16* atomh   = (u16*)(ws + O_FBP);
    u16* hW      = (u16*)(ws + O_BINPUT);   // binput dead after fused iter 3
    // t score ping-pong lives in d_out (overwritten by mol_attn2 at the end)
    float* tA = (float*)d_out;
    float* tB = tA + E_BONDS;

    // prep (weights only; fbonds consumed raw by the F32A GEMM)
    prep_wt<<<160, 256, 0, stream>>>(W_i, wti, 157, KPAD_I);
    prep_wt<<<256, 256, 0, stream>>>(W_h, wth, 256, 256);
    prep_wo<<<416, 256, 0, stream>>>(W_o_w, wto);
    prep_wt<<<256, 256, 0, stream>>>(W_a, wta, 256, 256);
    prep_wt<<<256, 256, 0, stream>>>(W_b_w, wtb, 256, 256);

    // binput = fbonds @ W_i (pre-relu stored) ; t0 = relu(binput) . Wma  — A staged from raw f32
    gemm256<1, false, true><<<1024, 512, 0, stream>>>(nullptr, wti, binput, nullptr, W_ma1, tA, KPAD_I, fbonds);

    // fused message iterations: gather is the A-stage of the W_h GEMM (Mp never materialized)
    fused_gg<1><<<E_BONDS / 64, 512, 0, stream>>>(binput, wth, bgraph, tA, binput, nullptr, nullptr, W_ma1, msgA, tB, nullptr, nullptr);
    fused_gg<0><<<E_BONDS / 64, 512, 0, stream>>>(msgA,   wth, bgraph, tB, binput, nullptr, nullptr, W_ma1, msgB, tA, nullptr, nullptr);
    fused_gg<0><<<E_BONDS / 64, 512, 0, stream>>>(msgB,   wth, bgraph, tA, binput, nullptr, nullptr, W_ma1, msgA, tB, nullptr, nullptr);

    // fused atom stage: agraph-gather + fatoms tail -> atomh = relu(.@W_o+b) ; + fused hW = atomh@W_a
    fused_gg<2><<<N_ATOMS_C / 32, 512, 0, stream>>>(msgA, wto, agraph, nullptr, nullptr, fatoms, W_o_b, nullptr, atomh, nullptr, wta, hW);

    // fused molecule tail: MFMA scores + softmax + PV + wtb GEMM + final reduce
    mol_attn2<<<N_MOLS, 256, 0, stream>>>(atomh, hW, wtb, W_b_b, out);
}